// Round 1
// 151.251 us; speedup vs baseline: 1.1545x; 1.1545x over previous
//
#include <hip/hip_runtime.h>
#include <hip/hip_bf16.h>

#define B_ 8
#define C_ 64
#define H_ 128
#define W_ 128
#define HW_ (H_ * W_)

typedef __attribute__((ext_vector_type(8))) short short8;
typedef __attribute__((ext_vector_type(4))) float float4v;
typedef _Float16 f16x2 __attribute__((ext_vector_type(2)));

static __device__ inline unsigned bfbits(float f) {
    __hip_bfloat16 h = __float2bfloat16(f);
    unsigned short s;
    __builtin_memcpy(&s, &h, 2);
    return (unsigned)s;
}

// f16x2 pair-dot with f32 accumulate (v_dot2_f32_f16); guarded fallback keeps
// the same numerics (full-precision products, f32 adds).
static __device__ inline float dot2(unsigned a, unsigned b, float c) {
    f16x2 ha, hb;
    __builtin_memcpy(&ha, &a, 4);
    __builtin_memcpy(&hb, &b, 4);
#if __has_builtin(__builtin_amdgcn_fdot2)
    return __builtin_amdgcn_fdot2(ha, hb, c, false);
#else
    return fmaf((float)ha.x, (float)hb.x, fmaf((float)ha.y, (float)hb.y, c));
#endif
}

static __device__ inline float2 up2(unsigned u) {
    f16x2 h;
    __builtin_memcpy(&h, &u, 4);
    return make_float2((float)h.x, (float)h.y);
}

// ---------------------------------------------------------------------------
// K0: repack W1|W2|W3 (fp32 [o][c]) into bf16 MFMA B-fragments, SPLIT hi/lo
// (unchanged; proj GEMM keeps its fp32-grade 3-term split).
// ---------------------------------------------------------------------------
__global__ void repack_w(const float* __restrict__ w1, const float* __restrict__ w2,
                         const float* __restrict__ w3,
                         unsigned short* __restrict__ wBhi, unsigned short* __restrict__ wBlo)
{
    const int i = blockIdx.x * 256 + threadIdx.x;
    if (i >= 12288) return;
    const int j = i & 7, lane = (i >> 3) & 63, ks = (i >> 9) & 1, nt = i >> 10;
    const int o = nt * 16 + (lane & 15);
    const int c = ks * 32 + (lane >> 4) * 8 + j;
    const float* wsel = (o < 64) ? w1 : (o < 128) ? w2 : w3;
    const float w = wsel[(o & 63) * 64 + c];
    const unsigned hb = bfbits(w);
    wBhi[i] = (unsigned short)hb;
    wBlo[i] = (unsigned short)bfbits(w - __uint_as_float(hb << 16));
}

// ---------------------------------------------------------------------------
// K1: QKV projection, unchanged math (3-term bf16 split MFMA, fp32 accum).
// ONLY the epilogue changed: q, k, v are all stored as fp16 now
// (2^-11 storage error; halves q/k write traffic 67 -> 33.5 MB).
// Layout stays [b][chunk4][HW][16] per tensor.
// ---------------------------------------------------------------------------
__global__ __launch_bounds__(256, 2) void proj_qkv(
    const float* __restrict__ x,
    const unsigned short* __restrict__ wBhi, const unsigned short* __restrict__ wBlo,
    _Float16* __restrict__ q, _Float16* __restrict__ k, _Float16* __restrict__ v)
{
    const int b = blockIdx.y;
    const int px0 = blockIdx.x * 128;
    const int t = threadIdx.x;
    const int lane = t & 63;
    const int wave_m = (t >> 6) & 1, wave_n = t >> 7;
    const int n = lane & 15, kg = lane >> 4;

    float4v acc[6][4];
    #pragma unroll
    for (int tnt = 0; tnt < 6; ++tnt)
        #pragma unroll
        for (int mt = 0; mt < 4; ++mt)
            acc[tnt][mt] = (float4v){0.f, 0.f, 0.f, 0.f};

    const float* xb = x + (size_t)b * C_ * HW_;
    const int pxl = px0 + wave_m * 64 + n;

    #pragma unroll
    for (int ks = 0; ks < 2; ++ks) {
        short8 ahi[4], alo[4];
        #pragma unroll
        for (int mt = 0; mt < 4; ++mt) {
            #pragma unroll
            for (int j = 0; j < 8; ++j) {
                const int c = ks * 32 + kg * 8 + j;
                const float f = xb[(size_t)c * HW_ + pxl + mt * 16];
                const unsigned hb = bfbits(f);
                ahi[mt][j] = (short)hb;
                alo[mt][j] = (short)bfbits(f - __uint_as_float(hb << 16));
            }
        }
        #pragma unroll
        for (int tnt = 0; tnt < 6; ++tnt) {
            const size_t bidx = (((size_t)(wave_n * 6 + tnt) * 2 + ks) * 64 + lane) * 8;
            short8 bh, bl;
            {
                const uint4 uh = *(const uint4*)(wBhi + bidx);
                const uint4 ul = *(const uint4*)(wBlo + bidx);
                __builtin_memcpy(&bh, &uh, 16);
                __builtin_memcpy(&bl, &ul, 16);
            }
            #pragma unroll
            for (int mt = 0; mt < 4; ++mt) {
                acc[tnt][mt] = __builtin_amdgcn_mfma_f32_16x16x32_bf16(
                    ahi[mt], bh, acc[tnt][mt], 0, 0, 0);
                acc[tnt][mt] = __builtin_amdgcn_mfma_f32_16x16x32_bf16(
                    alo[mt], bh, acc[tnt][mt], 0, 0, 0);
                acc[tnt][mt] = __builtin_amdgcn_mfma_f32_16x16x32_bf16(
                    ahi[mt], bl, acc[tnt][mt], 0, 0, 0);
            }
        }
    }

    // epilogue: D col = n (output o), row m = kg*4 + reg (pixel); fp16 stores
    #pragma unroll
    for (int tnt = 0; tnt < 6; ++tnt) {
        const int o_base = wave_n * 96 + tnt * 16;   // wave-uniform
        _Float16* base = (o_base < 64) ? q : (o_base < 128) ? k : v;
        const int chunk = (o_base >> 4) & 3;
        #pragma unroll
        for (int mt = 0; mt < 4; ++mt) {
            const int pxm = px0 + wave_m * 64 + mt * 16 + kg * 4;
            const float4v d = acc[tnt][mt];
            _Float16* p = base + (((size_t)b * 4 + chunk) * HW_ + pxm) * 16 + n;
            #pragma unroll
            for (int r = 0; r < 4; ++r) p[(size_t)r * 16] = (_Float16)d[r];
        }
    }
}

// ---------------------------------------------------------------------------
// K2: fused local attention, fp16 edition.
// All 64 channels of k (fp16, packed 2/word) fit in ONE 60.8 KB LDS tile:
//   8 uint4-planes of 484 halo px, plane stride 1944 words (bases mod 32 =
//   {0,24,16,8,...} -> even bank spread on both staging writes and b128 reads).
// Phase 1: q held in 32 VGPRs (8x uint4), scores via v_dot2_f32_f16
//   (8 b128 reads + 32 dot2 per offset -- half the LDS traffic and half the
//   FMA count of the fp32 version). No chunk loop: 3 barriers total (was 8).
// Phase 2: v fp16 staged into the same tile; acc[64] f32, unpack+fma
//   (fma_mix-fusable). grid (8,8,8), LDS 62208 B -> 2 blocks/CU.
// ---------------------------------------------------------------------------
#define HP_ 484                 // 22*22 halo pixels
#define PL_ 1944                // words per uint4-plane (484*4 + 8 pad)

__global__ __launch_bounds__(256, 2) void local_attn(
    const _Float16* __restrict__ q, const _Float16* __restrict__ k,
    const _Float16* __restrict__ v, float* __restrict__ out)
{
    __shared__ float tile[8 * PL_];
    const int b = blockIdx.z, h0 = blockIdx.y * 16, w0 = blockIdx.x * 16;
    const int t = threadIdx.x;
    const int pw = t & 15, ph = t >> 4;
    const size_t px = (size_t)(h0 + ph) * W_ + (w0 + pw);

    // q for own pixel: 4 chunks x 2 halves = 64 f16 in 8 uint4 (32 VGPR)
    uint4 qv[8];
    #pragma unroll
    for (int c8 = 0; c8 < 8; ++c8)
        qv[c8] = *(const uint4*)(q + (((size_t)b * 4 + (c8 >> 1)) * HW_ + px) * 16 + (c8 & 1) * 8);

    // ---- stage all of k (fp16, 8 planes) ----
    for (int i = t; i < HP_ * 8; i += 256) {
        const int pix = i >> 3, c8 = i & 7;
        const int r = pix / 22, cl = pix - r * 22;
        const int gh = h0 + r - 3, gw = w0 + cl - 3;
        uint4 val = make_uint4(0u, 0u, 0u, 0u);
        if (gh >= 0 && gh < H_ && gw >= 0 && gw < W_)
            val = *(const uint4*)(k + (((size_t)b * 4 + (c8 >> 1)) * HW_ +
                                       (size_t)gh * W_ + gw) * 16 + (c8 & 1) * 8);
        *(uint4*)(tile + c8 * PL_ + pix * 4) = val;
    }
    __syncthreads();

    // ---- phase 1: scores via dot2 ----
    float sc[49];
    #pragma unroll
    for (int dh = 0; dh < 7; ++dh) {
        #pragma unroll
        for (int dw = 0; dw < 7; ++dw) {
            const int np = ((ph + dh) * 22 + (pw + dw)) * 4;
            float s0 = 0.f, s1 = 0.f, s2 = 0.f, s3 = 0.f;
            #pragma unroll
            for (int p8 = 0; p8 < 8; ++p8) {
                const uint4 u = *(const uint4*)(tile + p8 * PL_ + np);
                s0 = dot2(qv[p8].x, u.x, s0);
                s1 = dot2(qv[p8].y, u.y, s1);
                s2 = dot2(qv[p8].z, u.z, s2);
                s3 = dot2(qv[p8].w, u.w, s3);
            }
            sc[dh * 7 + dw] = (s0 + s1) + (s2 + s3);
        }
    }

    // ---- softmax over 49 ----
    float m = sc[0];
    #pragma unroll
    for (int i = 1; i < 49; ++i) m = fmaxf(m, sc[i]);
    float s = 0.f;
    #pragma unroll
    for (int i = 0; i < 49; ++i) { sc[i] = __expf(sc[i] - m); s += sc[i]; }
    const float inv = 1.f / s;
    #pragma unroll
    for (int i = 0; i < 49; ++i) sc[i] *= inv;

    __syncthreads();            // all phase-1 reads done before overwrite

    // ---- stage all of v (fp16, same layout) ----
    for (int i = t; i < HP_ * 8; i += 256) {
        const int pix = i >> 3, c8 = i & 7;
        const int r = pix / 22, cl = pix - r * 22;
        const int gh = h0 + r - 3, gw = w0 + cl - 3;
        uint4 val = make_uint4(0u, 0u, 0u, 0u);
        if (gh >= 0 && gh < H_ && gw >= 0 && gw < W_)
            val = *(const uint4*)(v + (((size_t)b * 4 + (c8 >> 1)) * HW_ +
                                       (size_t)gh * W_ + gw) * 16 + (c8 & 1) * 8);
        *(uint4*)(tile + c8 * PL_ + pix * 4) = val;
    }
    __syncthreads();

    // ---- phase 2: weighting, acc over all 64 channels ----
    float acc[64];
    #pragma unroll
    for (int c = 0; c < 64; ++c) acc[c] = 0.f;
    #pragma unroll
    for (int dh = 0; dh < 7; ++dh) {
        #pragma unroll
        for (int dw = 0; dw < 7; ++dw) {
            const float wgt = sc[dh * 7 + dw];
            const int np = ((ph + dh) * 22 + (pw + dw)) * 4;
            #pragma unroll
            for (int p8 = 0; p8 < 8; ++p8) {
                const uint4 u = *(const uint4*)(tile + p8 * PL_ + np);
                const int a = p8 * 8;
                float2 f;
                f = up2(u.x); acc[a + 0] = fmaf(wgt, f.x, acc[a + 0]);
                              acc[a + 1] = fmaf(wgt, f.y, acc[a + 1]);
                f = up2(u.y); acc[a + 2] = fmaf(wgt, f.x, acc[a + 2]);
                              acc[a + 3] = fmaf(wgt, f.y, acc[a + 3]);
                f = up2(u.z); acc[a + 4] = fmaf(wgt, f.x, acc[a + 4]);
                              acc[a + 5] = fmaf(wgt, f.y, acc[a + 5]);
                f = up2(u.w); acc[a + 6] = fmaf(wgt, f.x, acc[a + 6]);
                              acc[a + 7] = fmaf(wgt, f.y, acc[a + 7]);
            }
        }
    }

    // ---- store: [b][64][HW], coalesced per channel ----
    #pragma unroll
    for (int c8 = 0; c8 < 8; ++c8) {
        const int ch0 = (c8 >> 1) * 16 + (c8 & 1) * 8;
        #pragma unroll
        for (int j = 0; j < 8; ++j)
            out[((size_t)b * 64 + ch0 + j) * HW_ + px] = acc[c8 * 8 + j];
    }
}

extern "C" void kernel_launch(void* const* d_in, const int* in_sizes, int n_in,
                              void* d_out, int out_size, void* d_ws, size_t ws_size,
                              hipStream_t stream) {
    const float* x  = (const float*)d_in[0];
    const float* w1 = (const float*)d_in[1];
    const float* w2 = (const float*)d_in[2];
    const float* w3 = (const float*)d_in[3];

    const size_t NE = (size_t)B_ * 4 * HW_ * 16;   // 8388608 elems per tensor
    _Float16* q = (_Float16*)d_ws;
    _Float16* k = q + NE;
    _Float16* v = k + NE;
    unsigned short* wBhi = (unsigned short*)(v + NE);  // 12288 ushorts
    unsigned short* wBlo = wBhi + 12288;
    float* o = (float*)d_out;

    repack_w<<<dim3(48), 256, 0, stream>>>(w1, w2, w3, wBhi, wBlo);
    proj_qkv<<<dim3(HW_ / 128, B_), 256, 0, stream>>>(x, wBhi, wBlo, q, k, v);
    local_attn<<<dim3(W_ / 16, H_ / 16, B_), 256, 0, stream>>>(q, k, v, o);
}